// Round 6
// baseline (1779.087 us; speedup 1.0000x reference)
//
#include <hip/hip_runtime.h>
#include <hip/hip_bf16.h>
#include <stdint.h>
#include <math.h>

#define B   64
#define T   1000
#define INP 64
#define HID 512
#define ACT 2

#define NSLICE 4                    // column slices per row-group
#define MROWS  2                    // batch rows per block
#define NGROUP (B / MROWS)          // 32 row-groups
#define NBLOCKS (NGROUP * NSLICE)   // 128 worker slots
#define NLAUNCH 256                 // launched blocks (claim surplus)
#define WORK_PER_XCD 16             // 4 groups x 4 slices per XCD
#define COLS   (HID / NSLICE)       // 128 cols per block
#define NWAVES 4                    // 4 waves x 32 cols (2 n-tiles) each
#define HLPAD  544                  // row stride (shorts): bank shift 16/row

#define FAST_GUARD 256              // fast-poll budget (sticky demotion)
#define SAFE_GUARD (1 << 18)        // MALL-poll budget (fail fast, no hang)

typedef __attribute__((ext_vector_type(8))) short short8;     // 8 bf16
typedef __attribute__((ext_vector_type(4))) float floatx4;    // MFMA C/D
typedef __attribute__((ext_vector_type(4))) uint32_t uint32x4;

// ---------------------------------------------------------------------------
// L2 fast-path primitives (same-XCD L2 shared by all CUs on the XCD):
//   load : sc0 = bypass L1, read the XCD's L2
//   store: plain = write-through L1 into own-XCD L2
// Visibility is NOT treated as guaranteed: producers dual-store (h_fast
// plain + h_safe agent-scope/MALL); consumers fast-poll with a bounded
// budget and sticky per-wave fallback to the MALL path (round-3 lesson:
// removing this net corrupts — the fast path is flaky for some waves).
// ---------------------------------------------------------------------------
__device__ __forceinline__ uint32x4 l2_load128(const void* p) {
  uint32x4 v;
  asm volatile("global_load_dwordx4 %0, %1, off sc0\n\t"
               "s_waitcnt vmcnt(0)"
               : "=v"(v) : "v"(p) : "memory");
  return v;
}
__device__ __forceinline__ void l2_store64(uint64_t* p, uint64_t v) {
  asm volatile("global_store_dwordx2 %0, %1, off"
               :: "v"(p), "v"(v) : "memory");
}
__device__ __forceinline__ int get_xcc_id() {
  int x;
  asm volatile("s_getreg_b32 %0, hwreg(HW_REG_XCC_ID)" : "=s"(x));
  return x & 7;
}

// ctrl layout (u32): [0..7] per-XCD claim counters, [8] claimed, [9] arrivals,
// [10] mode flag (0=undecided, 1=fallback layout, 2=XCD layout)
#define CTRL_WORDS 16

// ---------------------------------------------------------------------------
// Exchange word layout: [parity][group][col] -> u64 = (row1 << 32) | row0,
// each u32 = (bf16 bits << 16) | (step_tag & 0xFFFF); h_t carries tag t+1.
// K0: init — hn -> tagged words, parity-1, tag 0 (=h_{-1}); poison parity-0;
// zero the ctrl block.
// ---------------------------------------------------------------------------
__global__ __launch_bounds__(256) void init_kernel(
    const float* __restrict__ hn, uint64_t* __restrict__ h_fast,
    uint64_t* __restrict__ h_safe, uint32_t* __restrict__ ctrl) {
  if (blockIdx.x == 0 && threadIdx.x < CTRL_WORDS) ctrl[threadIdx.x] = 0;
  const int i   = blockIdx.x * 256 + threadIdx.x;  // 0 .. NGROUP*HID-1
  const int g   = i >> 9;                          // / HID
  const int col = i & (HID - 1);
  __hip_bfloat16 b0 = __float2bfloat16(hn[(2 * g) * HID + col]);
  __hip_bfloat16 b1 = __float2bfloat16(hn[(2 * g + 1) * HID + col]);
  const uint32_t w0 = ((uint32_t)*reinterpret_cast<unsigned short*>(&b0)) << 16;
  const uint32_t w1 = ((uint32_t)*reinterpret_cast<unsigned short*>(&b1)) << 16;
  const uint64_t v  = (uint64_t)w0 | ((uint64_t)w1 << 32);  // tag 0
  const size_t p1 = (size_t)NGROUP * HID + i;               // parity 1
  h_fast[p1] = v;
  h_safe[p1] = v;
  h_fast[i] = 0x0000FFFE0000FFFEull;  // parity 0: non-matching tag
  h_safe[i] = 0x0000FFFE0000FFFEull;
}

// ---------------------------------------------------------------------------
// K1: xproj[b,t,:] = inp[b,t,:] @ W_ih  -> rnn slab (overwritten by h later)
// ---------------------------------------------------------------------------
__global__ __launch_bounds__(256) void xproj_kernel(
    const float* __restrict__ inp, const float* __restrict__ W_ih,
    float* __restrict__ rnn) {
  __shared__ float xin[16 * INP];
  const int tid = threadIdx.x;
  const long r0 = (long)blockIdx.x * 16;

  const float4* inp4 = (const float4*)(inp + r0 * INP);
  ((float4*)xin)[tid] = inp4[tid];
  __syncthreads();

  const int j = tid, j2 = tid + 256;
  float acc0[16], acc1[16];
#pragma unroll
  for (int r = 0; r < 16; ++r) { acc0[r] = 0.f; acc1[r] = 0.f; }

  for (int i = 0; i < INP; ++i) {
    const float w0 = W_ih[i * HID + j];
    const float w1 = W_ih[i * HID + j2];
#pragma unroll
    for (int r = 0; r < 16; ++r) {
      const float x = xin[r * INP + i];
      acc0[r] = fmaf(x, w0, acc0[r]);
      acc1[r] = fmaf(x, w1, acc1[r]);
    }
  }
#pragma unroll
  for (int r = 0; r < 16; ++r) {
    rnn[(r0 + r) * HID + j]  = acc0[r];
    rnn[(r0 + r) * HID + j2] = acc1[r];
  }
}

// ---------------------------------------------------------------------------
// K2: recurrence, 4-wave geometry. Each wave owns 2 n-tiles (32 cols) and
// shares each A-fragment ds_read across both — halves per-CU LDS A-read
// traffic vs the 8-wave layout and halves barrier width. Exchange protocol
// identical to the round-2-proven version (dual store + sticky fallback).
// ---------------------------------------------------------------------------
__global__ __launch_bounds__(256, 1) void rnn_mfma(
    const float* __restrict__ W_hh, float* __restrict__ rnn,
    float* __restrict__ hn_out, uint64_t* __restrict__ h_fast,
    uint64_t* __restrict__ h_safe, uint32_t* __restrict__ ctrl) {
  // [parity][row][col] with row stride 544 shorts (1088 B -> bank shift 16)
  __shared__ __align__(16) unsigned short hl[2][MROWS][HLPAD];
  __shared__ int sh_g, sh_s, sh_work, sh_mode;

  const int tid  = threadIdx.x;

  // ---- claim a (group, slice) slot on this block's physical XCD
  if (tid == 0) {
    uint32_t* cnt      = ctrl;          // [8]
    uint32_t* claimed  = ctrl + 8;
    uint32_t* arrivals = ctrl + 9;
    uint32_t* flag     = ctrl + 10;
    const int xcc = get_xcc_id();
    const int slot = (int)__hip_atomic_fetch_add(
        &cnt[xcc], 1u, __ATOMIC_RELAXED, __HIP_MEMORY_SCOPE_AGENT);
    int work = 0, g = 0, s = 0;
    if (slot < WORK_PER_XCD) {          // groups [4*xcc, 4*xcc+4) x 4 slices
      g = xcc * 4 + (slot >> 2);
      s = slot & 3;
      work = 1;
      __hip_atomic_fetch_add(claimed, 1u, __ATOMIC_RELEASE,
                             __HIP_MEMORY_SCOPE_AGENT);
    }
    const int arr = (int)__hip_atomic_fetch_add(
        arrivals, 1u, __ATOMIC_ACQ_REL, __HIP_MEMORY_SCOPE_AGENT);
    if (arr == NLAUNCH - 1) {           // last arriver decides, once, for all
      const uint32_t c = __hip_atomic_load(claimed, __ATOMIC_ACQUIRE,
                                           __HIP_MEMORY_SCOPE_AGENT);
      __hip_atomic_store(flag, (c == NBLOCKS) ? 2u : 1u, __ATOMIC_RELEASE,
                         __HIP_MEMORY_SCOPE_AGENT);
    }
    uint32_t f = 0; int guard = 0;
    do {
      f = __hip_atomic_load(flag, __ATOMIC_ACQUIRE, __HIP_MEMORY_SCOPE_AGENT);
    } while (f == 0 && ++guard < (1 << 20));
    if (f != 2) {                       // globally-consistent fallback layout
      work = (blockIdx.x < NBLOCKS);
      g = blockIdx.x & (NGROUP - 1);
      s = blockIdx.x >> 5;
    }
    sh_g = g; sh_s = s; sh_work = work; sh_mode = (f == 2);
  }
  __syncthreads();
  if (!sh_work) return;                 // block-uniform: no further barriers

  const int g = __builtin_amdgcn_readfirstlane(sh_g);
  const int s = __builtin_amdgcn_readfirstlane(sh_s);
  int fastmode = __builtin_amdgcn_readfirstlane(sh_mode);  // sticky per wave

  const int lane = tid & 63;
  const int w    = tid >> 6;              // wave 0..3
  const int r0   = g * MROWS;
  const int n_base = s * COLS + w * 32;   // wave covers 32 cols, 2 n-tiles

  const int lm = lane & 15;               // MFMA m/n lane index
  const int lq = lane >> 4;               // quad 0..3 -> k-subchunk
  const int cca = n_base + lm;            // n-tile 0 column
  const int ccb = cca + 16;               // n-tile 1 column

  // ---- one-time: W_hh column slices -> bf16 B-frags (2 tiles per wave)
  short8 bfA[16], bfB[16];
#pragma unroll
  for (int kt = 0; kt < 16; ++kt) {
    short8 fa, fb;
#pragma unroll
    for (int i = 0; i < 8; ++i) {
      const int k = kt * 32 + lq * 8 + i;
      __hip_bfloat16 ha = __float2bfloat16(W_hh[k * HID + cca]);
      __hip_bfloat16 hb = __float2bfloat16(W_hh[k * HID + ccb]);
      fa[i] = *reinterpret_cast<short*>(&ha);
      fb[i] = *reinterpret_cast<short*>(&hb);
    }
    bfA[kt] = fa;
    bfB[kt] = fb;
  }

  const int  arow   = lm & 1;             // A row duplication (M=2 real rows)
  const bool remote = (w != s);           // wave-uniform: wave w polls slice w
  const bool prod   = (lq == 0);          // producer lanes (hold C rows 0,1)

  // xp double-buffer: producer lanes, 2 cols x 2 rows
  long roa0 = ((long)r0 * T) * HID + cca;
  long roa1 = ((long)(r0 + 1) * T) * HID + cca;
  long rob0 = roa0 + 16, rob1 = roa1 + 16;
  float xpa0 = 0.f, xpa1 = 0.f, xpb0 = 0.f, xpb1 = 0.f;
  if (prod) {
    xpa0 = rnn[roa0]; xpa1 = rnn[roa1];
    xpb0 = rnn[rob0]; xpb1 = rnn[rob1];
  }

  for (int t = 0; t < T; ++t) {
    const int p = (t + 1) & 1;            // parity holding h_{t-1}

    // ---- poll tagged words: thread covers cols 2*tid, 2*tid+1 (1 dwordx4)
    if (t == 0 || remote) {
      const size_t idx = ((size_t)p * NGROUP + g) * HID + 2 * tid;
      const uint32_t want = (uint32_t)t & 0xFFFFu;
      uint32x4 v = {0, 0, 0, 0};
      if (fastmode) {
        int ok = 0;
        for (int it = 0; it < FAST_GUARD; ++it) {
          v = l2_load128(h_fast + idx);
          if ((((v[0] ^ want) | (v[1] ^ want) | (v[2] ^ want) |
                (v[3] ^ want)) & 0xFFFFu) == 0) { ok = 1; break; }
        }
        if (!ok) fastmode = 0;            // flaky visibility: demote to MALL
      }
      if (!fastmode) {                    // guaranteed path via MALL
        int guard = 0;
        for (;;) {
          const uint64_t a = __hip_atomic_load(h_safe + idx, __ATOMIC_RELAXED,
                                               __HIP_MEMORY_SCOPE_AGENT);
          const uint64_t b = __hip_atomic_load(h_safe + idx + 1,
                                               __ATOMIC_RELAXED,
                                               __HIP_MEMORY_SCOPE_AGENT);
          v[0] = (uint32_t)a; v[1] = (uint32_t)(a >> 32);
          v[2] = (uint32_t)b; v[3] = (uint32_t)(b >> 32);
          if ((((v[0] ^ want) | (v[1] ^ want) | (v[2] ^ want) |
                (v[3] ^ want)) & 0xFFFFu) == 0) break;
          if (++guard > SAFE_GUARD) break; // never hang the harness
        }
      }
      // stage: row0 cols (2t,2t+1) as one b32; same for row1
      *reinterpret_cast<uint32_t*>(&hl[p][0][2 * tid]) =
          (v[0] >> 16) | (v[2] & 0xFFFF0000u);
      *reinterpret_cast<uint32_t*>(&hl[p][1][2 * tid]) =
          (v[1] >> 16) | (v[3] & 0xFFFF0000u);
    }
    __syncthreads();                      // one barrier/step (parity dbuf)

    // prefetch next step's xproj (hidden under MFMA + next poll)
    float na0 = 0.f, na1 = 0.f, nb0 = 0.f, nb1 = 0.f;
    if (prod && t + 1 < T) {
      na0 = rnn[roa0 + HID]; na1 = rnn[roa1 + HID];
      nb0 = rnn[rob0 + HID]; nb1 = rnn[rob1 + HID];
    }

    // ---- 32 MFMA over k x 2 tiles; each A-read feeds both tiles
    floatx4 c0a = {0.f, 0.f, 0.f, 0.f}, c1a = c0a, c2a = c0a, c3a = c0a;
    floatx4 c0b = c0a, c1b = c0a, c2b = c0a, c3b = c0a;
    const unsigned short* ap = &hl[p][arow][lq * 8];
#pragma unroll
    for (int kt = 0; kt < 16; kt += 4) {
      short8 a0 = *(const short8*)(ap + (kt + 0) * 32);
      short8 a1 = *(const short8*)(ap + (kt + 1) * 32);
      short8 a2 = *(const short8*)(ap + (kt + 2) * 32);
      short8 a3 = *(const short8*)(ap + (kt + 3) * 32);
      c0a = __builtin_amdgcn_mfma_f32_16x16x32_bf16(a0, bfA[kt + 0], c0a, 0, 0, 0);
      c0b = __builtin_amdgcn_mfma_f32_16x16x32_bf16(a0, bfB[kt + 0], c0b, 0, 0, 0);
      c1a = __builtin_amdgcn_mfma_f32_16x16x32_bf16(a1, bfA[kt + 1], c1a, 0, 0, 0);
      c1b = __builtin_amdgcn_mfma_f32_16x16x32_bf16(a1, bfB[kt + 1], c1b, 0, 0, 0);
      c2a = __builtin_amdgcn_mfma_f32_16x16x32_bf16(a2, bfA[kt + 2], c2a, 0, 0, 0);
      c2b = __builtin_amdgcn_mfma_f32_16x16x32_bf16(a2, bfB[kt + 2], c2b, 0, 0, 0);
      c3a = __builtin_amdgcn_mfma_f32_16x16x32_bf16(a3, bfA[kt + 3], c3a, 0, 0, 0);
      c3b = __builtin_amdgcn_mfma_f32_16x16x32_bf16(a3, bfB[kt + 3], c3b, 0, 0, 0);
    }

    if (prod) {  // C layout: col = lane&15, row = (lane>>4)*4 + reg
      const float za0 = (c0a[0] + c1a[0]) + (c2a[0] + c3a[0]) + xpa0;
      const float za1 = (c0a[1] + c1a[1]) + (c2a[1] + c3a[1]) + xpa1;
      const float zb0 = (c0b[0] + c1b[0]) + (c2b[0] + c3b[0]) + xpb0;
      const float zb1 = (c0b[1] + c1b[1]) + (c2b[1] + c3b[1]) + xpb1;
      const float ha0 = 1.f / (1.f + __expf(-za0));
      const float ha1 = 1.f / (1.f + __expf(-za1));
      const float hb0 = 1.f / (1.f + __expf(-zb0));
      const float hb1 = 1.f / (1.f + __expf(-zb1));
      __hip_bfloat16 ba0 = __float2bfloat16(ha0);
      __hip_bfloat16 ba1 = __float2bfloat16(ha1);
      __hip_bfloat16 bb0 = __float2bfloat16(hb0);
      __hip_bfloat16 bb1 = __float2bfloat16(hb1);
      const unsigned short ua0 = *reinterpret_cast<unsigned short*>(&ba0);
      const unsigned short ua1 = *reinterpret_cast<unsigned short*>(&ba1);
      const unsigned short ub0 = *reinterpret_cast<unsigned short*>(&bb0);
      const unsigned short ub1 = *reinterpret_cast<unsigned short*>(&bb1);

      // critical path first: tagged words, dual-published (L2 + MALL)
      const uint32_t tag = (uint32_t)(t + 1) & 0xFFFFu;
      const uint64_t worda =
          (uint64_t)(((uint32_t)ua0 << 16) | tag) |
          ((uint64_t)(((uint32_t)ua1 << 16) | tag) << 32);
      const uint64_t wordb =
          (uint64_t)(((uint32_t)ub0 << 16) | tag) |
          ((uint64_t)(((uint32_t)ub1 << 16) | tag) << 32);
      const size_t dbase = ((size_t)(t & 1) * NGROUP + g) * HID;
      l2_store64(h_fast + dbase + cca, worda);
      l2_store64(h_fast + dbase + ccb, wordb);
      __hip_atomic_store(h_safe + dbase + cca, worda, __ATOMIC_RELAXED,
                         __HIP_MEMORY_SCOPE_AGENT);
      __hip_atomic_store(h_safe + dbase + ccb, wordb, __ATOMIC_RELAXED,
                         __HIP_MEMORY_SCOPE_AGENT);

      // own-slice bypass: stage h_t for our own next step directly in LDS
      hl[t & 1][0][cca] = ua0;
      hl[t & 1][1][cca] = ua1;
      hl[t & 1][0][ccb] = ub0;
      hl[t & 1][1][ccb] = ub1;

      // non-critical: f32 outputs
      rnn[roa0] = ha0; rnn[roa1] = ha1;
      rnn[rob0] = hb0; rnn[rob1] = hb1;
      if (t == T - 1) {
        hn_out[r0 * HID + cca]       = ha0;
        hn_out[(r0 + 1) * HID + cca] = ha1;
        hn_out[r0 * HID + ccb]       = hb0;
        hn_out[(r0 + 1) * HID + ccb] = hb1;
      }
      xpa0 = na0; xpa1 = na1; xpb0 = nb0; xpb1 = nb1;
      roa0 += HID; roa1 += HID; rob0 += HID; rob1 += HID;
    }
  }
}

// ---------------------------------------------------------------------------
// K3: out[b,t,:] = sigmoid(rnn[b,t,:] @ W_fc + b_fc)
// ---------------------------------------------------------------------------
__global__ __launch_bounds__(256) void fc_kernel(
    const float* __restrict__ rnn, const float* __restrict__ W_fc,
    const float* __restrict__ b_fc, float* __restrict__ out) {
  const int lane = threadIdx.x & 63;
  const int wid  = threadIdx.x >> 6;
  const long row = (long)blockIdx.x * 4 + wid;

  const float4* __restrict__ hrow = (const float4*)(rnn + row * HID);
  const float4* __restrict__ Wfc4 = (const float4*)W_fc;

  float a0 = 0.f, a1 = 0.f;
#pragma unroll
  for (int u = 0; u < 2; ++u) {
    const float4 hv = hrow[lane * 2 + u];
    const int j0 = lane * 8 + u * 4;
    const float4 wA = Wfc4[(j0 >> 1)];
    const float4 wB = Wfc4[(j0 >> 1) + 1];
    a0 += hv.x * wA.x + hv.y * wA.z + hv.z * wB.x + hv.w * wB.z;
    a1 += hv.x * wA.y + hv.y * wA.w + hv.z * wB.y + hv.w * wB.w;
  }
#pragma unroll
  for (int off = 32; off > 0; off >>= 1) {
    a0 += __shfl_down(a0, off, 64);
    a1 += __shfl_down(a1, off, 64);
  }
  if (lane == 0) {
    out[row * 2 + 0] = 1.f / (1.f + __expf(-(a0 + b_fc[0])));
    out[row * 2 + 1] = 1.f / (1.f + __expf(-(a1 + b_fc[1])));
  }
}

// ---------------------------------------------------------------------------
extern "C" void kernel_launch(void* const* d_in, const int* in_sizes, int n_in,
                              void* d_out, int out_size, void* d_ws,
                              size_t ws_size, hipStream_t stream) {
  const float* inp  = (const float*)d_in[0];
  const float* hn   = (const float*)d_in[1];
  const float* W_hh = (const float*)d_in[2];
  const float* W_ih = (const float*)d_in[3];
  const float* W_fc = (const float*)d_in[4];
  const float* b_fc = (const float*)d_in[5];

  float* out    = (float*)d_out;              // [B,T,ACT]
  float* hn_out = out + (long)B * T * ACT;    // [1,B,HID]
  float* rnn    = hn_out + (long)B * HID;     // [B,T,HID]

  // workspace: ctrl (256 B) | h_fast[2][NGROUP][HID] u64 (256 KB) | h_safe
  uint32_t* ctrl   = (uint32_t*)d_ws;
  uint64_t* h_fast = (uint64_t*)((char*)d_ws + 256);
  const size_t HCNT = (size_t)2 * NGROUP * HID;             // u64 words
  uint64_t* h_safe =
      (ws_size >= 256 + 2 * HCNT * sizeof(uint64_t)) ? (h_fast + HCNT)
                                                     : h_fast;  // alias-safe

  hipLaunchKernelGGL(init_kernel, dim3((NGROUP * HID) / 256), dim3(256), 0,
                     stream, hn, h_fast, h_safe, ctrl);
  hipLaunchKernelGGL(xproj_kernel, dim3((B * T) / 16), dim3(256), 0, stream,
                     inp, W_ih, rnn);
  hipLaunchKernelGGL(rnn_mfma, dim3(NLAUNCH), dim3(256), 0, stream,
                     W_hh, rnn, hn_out, h_fast, h_safe, ctrl);
  hipLaunchKernelGGL(fc_kernel, dim3((B * T) / 4), dim3(256), 0, stream,
                     rnn, W_fc, b_fc, out);
}